// Round 12
// baseline (186.999 us; speedup 1.0000x reference)
//
#include <hip/hip_runtime.h>
#include <stdint.h>

// ---------------------------------------------------------------------------
// VarianceMaximizationCovarianceMinimizationLoss on MI355X
//   features [65536,2,256] fp32, labels [65536] int32 -> scalar fp32 loss
// Round 12: two-phase streaming (requires ws >= ~79 MB, else round-11 path):
//   k_tr     : gather rows via idx, transpose to COLUMN-major bf16 chunk
//              slabs sortedT[chunk][256 f][512 r] (+ fused fp32 col sums).
//              Pure streaming, no barriers.
//   k_gram_s : quadrant Grams with MFMA fragments loaded DIRECTLY from
//              global (k-contiguous in column-major layout). No LDS, no
//              __syncthreads -> waves independent, latency hidden by TLP.
//   k_loss_s : sum G group-slabs -> cov -> loss.
// Fallback (ws too small): round-11 fused kernels (proven, 134 us).
// ---------------------------------------------------------------------------

#define NCLS  8
#define D     256
#define CHUNK 512
#define SEG   256
#define EPSF  1e-4f
#define TCMAX 263        // sum_c ceil(n_c/512) <= 256+7
#define TMAXF 264        // fallback bound
#define QLEN  16384      // 128x128 slab

typedef __bf16 bf16x8 __attribute__((ext_vector_type(8)));
typedef float  f32x4  __attribute__((ext_vector_type(4)));

__device__ __forceinline__ unsigned short f2bf(float f) {
    unsigned int x = __float_as_uint(f);
    x += 0x7fffu + ((x >> 16) & 1u);
    return (unsigned short)(x >> 16);
}
__device__ __forceinline__ float bf2f(unsigned short u) {
    return __uint_as_float(((unsigned int)u) << 16);
}

// ---- k1a: histogram -------------------------------------------------------
__global__ void k_hist(const int* __restrict__ labels, int nlab, int vfac,
                       int* __restrict__ counts) {
    __shared__ int lc[NCLS];
    int t = threadIdx.x;
    if (t < NCLS) lc[t] = 0;
    __syncthreads();
    for (int i = blockIdx.x * blockDim.x + t; i < nlab; i += gridDim.x * blockDim.x)
        atomicAdd(&lc[labels[i] & 7], vfac);
    __syncthreads();
    if (t < NCLS && lc[t]) atomicAdd(&counts[t], lc[t]);
}

// ---- k1b: offsets + cursors ----------------------------------------------
__global__ void k_offsets(const int* __restrict__ counts,
                          int* __restrict__ offsets, int* __restrict__ cursor) {
    if (threadIdx.x == 0) {
        int acc = 0;
        for (int c = 0; c < NCLS; ++c) { offsets[c] = acc; cursor[c] = acc; acc += counts[c]; }
    }
}

// ---- k2: class-sorted row-index array -------------------------------------
__global__ __launch_bounds__(256) void k_idx(
    const int* __restrict__ labels, int nrows, int vfac,
    int* __restrict__ cursor, int* __restrict__ idx)
{
    __shared__ int lcnt[NCLS], lbase[NCLS];
    int t = threadIdx.x;
    int row = blockIdx.x * SEG + t;
    if (t < NCLS) lcnt[t] = 0;
    __syncthreads();
    int c = 0, rk = 0;
    bool ok = (row < nrows);
    if (ok) {
        c = labels[row / vfac] & 7;
        rk = atomicAdd(&lcnt[c], 1);
    }
    __syncthreads();
    if (t < NCLS) lbase[t] = lcnt[t] ? atomicAdd(&cursor[t], lcnt[t]) : 0;
    __syncthreads();
    if (ok) idx[lbase[c] + rk] = row;
}

// ---- k_tr: gather + transpose to column-major bf16 chunk slabs ------------
// WG = 512 threads handles one (chunk, col-half): thread (fg=t>>5 0-15,
// rg=t&31), per pass p: reads 4 rows x 4 cols fp32, writes 4 x 8B
// (f, r0..r0+3) -> 256 B contiguous runs per (fg, j). Tail rows zero-filled.
__global__ __launch_bounds__(512) void k_tr(
    const float* __restrict__ X, const int* __restrict__ idx,
    const int* __restrict__ counts, const int* __restrict__ offsets,
    unsigned short* __restrict__ sortedT, float* __restrict__ csums)
{
    int t = threadIdx.x;
    int fg = t >> 5, rg = t & 31;

    int nch[NCLS], ofch[NCLS];
    int T = 0;
    for (int c = 0; c < NCLS; ++c) {
        nch[c] = (counts[c] + CHUNK - 1) / CHUNK;
        ofch[c] = T;
        T += nch[c];
    }
    const f32x4 zf = {0.f, 0.f, 0.f, 0.f};

    for (int wk = blockIdx.x; wk < 2 * T; wk += gridDim.x) {
        int ch = wk >> 1, ph = wk & 1;
        int c = 0;
        while (c < NCLS - 1 && ch >= ofch[c + 1]) ++c;
        int m = ch - ofch[c];
        int base = offsets[c] + m * CHUNK;
        int rows = min(CHUNK, counts[c] - m * CHUNK);
        unsigned short* out = sortedT + ((size_t)ch << 17);   // 131072 elems

        for (int p = ph * 2; p < ph * 2 + 2; ++p) {
            float s0 = 0.f, s1 = 0.f, s2 = 0.f, s3 = 0.f;
            for (int it = 0; it < 4; ++it) {
                int r0 = it * 128 + rg * 4;
                f32x4 v[4];
                #pragma unroll
                for (int j = 0; j < 4; ++j) {
                    int r = r0 + j;
                    int rid = idx[base + min(r, rows - 1)];
                    f32x4 x = *(const f32x4*)(X + ((size_t)rid << 8) + p * 64 + fg * 4);
                    if (r >= rows) x = zf;
                    v[j] = x;
                }
                s0 += v[0][0] + v[1][0] + v[2][0] + v[3][0];
                s1 += v[0][1] + v[1][1] + v[2][1] + v[3][1];
                s2 += v[0][2] + v[1][2] + v[2][2] + v[3][2];
                s3 += v[0][3] + v[1][3] + v[2][3] + v[3][3];
                #pragma unroll
                for (int e = 0; e < 4; ++e) {
                    unsigned int b0 = (unsigned int)f2bf(v[0][e]) | ((unsigned int)f2bf(v[1][e]) << 16);
                    unsigned int b1 = (unsigned int)f2bf(v[2][e]) | ((unsigned int)f2bf(v[3][e]) << 16);
                    int f = p * 64 + fg * 4 + e;
                    *(uint2*)(out + (size_t)f * CHUNK + r0) = make_uint2(b0, b1);
                }
            }
            // reduce over rg (32 lanes; xor masks stay within half-wave)
            #pragma unroll
            for (int sh = 1; sh < 32; sh <<= 1) {
                s0 += __shfl_xor(s0, sh, 64);
                s1 += __shfl_xor(s1, sh, 64);
                s2 += __shfl_xor(s2, sh, 64);
                s3 += __shfl_xor(s3, sh, 64);
            }
            if (rg == 0) {
                f32x4 sv = {s0, s1, s2, s3};
                *(f32x4*)(csums + (size_t)ch * D + p * 64 + fg * 4) = sv;
            }
        }
    }
}

// ---- k_gram_s: quadrant Grams, fragments direct from global ---------------
// WG = 256 (4 waves as 2x2 over the 128x128 quadrant). No LDS, no barriers.
// Work item wk -> (c, q, g): class c, quadrant q (0:[0,0] 1:[128,128]
// 2:[0,128]), group g handles chunks m = g, g+G, ... of class c.
__global__ __launch_bounds__(256) void k_gram_s(
    const unsigned short* __restrict__ sortedT, const int* __restrict__ counts,
    unsigned short* __restrict__ part, int G)
{
    int t = threadIdx.x;
    int lane = t & 63;
    int w = t >> 6;
    int wr = w >> 1, wc = w & 1;

    int wk = blockIdx.x;
    int c = wk / (3 * G);
    int rem = wk - c * (3 * G);
    int q = rem / G;
    int g = rem - q * G;

    int och = 0;
    for (int cc = 0; cc < c; ++cc) och += (counts[cc] + CHUNK - 1) / CHUNK;
    int nchc = (counts[c] + CHUNK - 1) / CHUNK;

    int rowb = (q == 1) ? 128 : 0;
    int colb = (q == 0) ? 0 : 128;
    int fr_a = rowb + wr * 64 + (lane & 15);
    int fr_b = colb + wc * 64 + (lane & 15);
    int kh = (lane >> 4) * 8;

    f32x4 acc[4][4];
    #pragma unroll
    for (int i = 0; i < 4; ++i)
        #pragma unroll
        for (int j = 0; j < 4; ++j)
            #pragma unroll
            for (int r = 0; r < 4; ++r) acc[i][j][r] = 0.f;

    for (int m = g; m < nchc; m += G) {
        const unsigned short* cb = sortedT + ((size_t)(och + m) << 17);
        const unsigned short* pa = cb + (size_t)fr_a * CHUNK + kh;
        const unsigned short* pb = cb + (size_t)fr_b * CHUNK + kh;
        for (int ks = 0; ks < CHUNK / 32; ++ks) {
            int ke = ks * 32;
            bf16x8 afr[4], bfr[4];
            #pragma unroll
            for (int ti = 0; ti < 4; ++ti)
                afr[ti] = __builtin_bit_cast(bf16x8,
                    *(const uint4*)(pa + (size_t)ti * 16 * CHUNK + ke));
            #pragma unroll
            for (int tj = 0; tj < 4; ++tj)
                bfr[tj] = __builtin_bit_cast(bf16x8,
                    *(const uint4*)(pb + (size_t)tj * 16 * CHUNK + ke));
            #pragma unroll
            for (int ti = 0; ti < 4; ++ti)
                #pragma unroll
                for (int tj = 0; tj < 4; ++tj)
                    acc[ti][tj] = __builtin_amdgcn_mfma_f32_16x16x32_bf16(
                        afr[ti], bfr[tj], acc[ti][tj], 0, 0, 0);
        }
    }

    // flush 64x64 portion of the 128x128 bf16 slab (always, even if zero)
    unsigned short* dst = part + (size_t)wk * QLEN;
    #pragma unroll
    for (int ti = 0; ti < 4; ++ti) {
        int row0 = wr * 64 + ti * 16 + ((lane >> 4) << 2);
        #pragma unroll
        for (int tj = 0; tj < 4; ++tj) {
            int col = wc * 64 + tj * 16 + (lane & 15);
            #pragma unroll
            for (int r = 0; r < 4; ++r)
                dst[(row0 + r) * 128 + col] = f2bf(acc[ti][tj][r]);
        }
    }
}

// ---- k_gsum ---------------------------------------------------------------
__global__ __launch_bounds__(256) void k_gsum(
    const float* __restrict__ csums, const int* __restrict__ counts,
    float* __restrict__ gsums)
{
    int c = blockIdx.x;
    int i = threadIdx.x;
    int of = 0;
    for (int cc = 0; cc < c; ++cc) of += (counts[cc] + CHUNK - 1) / CHUNK;
    int nc = (counts[c] + CHUNK - 1) / CHUNK;
    float s = 0.f;
    for (int q = 0; q < nc; ++q) s += csums[(size_t)(of + q) * D + i];
    gsums[c * D + i] = s;
}

// ---- k_loss_s: loss from (c,q,g) group slabs ------------------------------
__global__ __launch_bounds__(256) void k_loss_s(
    const unsigned short* __restrict__ part, const float* __restrict__ gsums,
    const int* __restrict__ counts, float* __restrict__ out, int G)
{
    __shared__ float red[256];
    int t = threadIdx.x;
    float local = 0.f;
    const int total = NCLS * 3 * QLEN;
    for (int idx = blockIdx.x * blockDim.x + t; idx < total; idx += gridDim.x * blockDim.x) {
        int c = idx / (3 * QLEN);
        int rem = idx - c * (3 * QLEN);
        int q = rem >> 14;
        int ij = rem & (QLEN - 1);
        int il = ij >> 7, jl = ij & 127;
        int gi = il + ((q == 1) ? 128 : 0);
        int gj = jl + ((q == 0) ? 0 : 128);
        const unsigned short* p = part + ((size_t)((c * 3 + q) * G)) * QLEN + ij;
        float s = 0.f;
        for (int g = 0; g < G; ++g) s += bf2f(p[(size_t)g * QLEN]);
        float n  = (float)counts[c];
        float mi = gsums[c * D + gi] / n;
        float mj = gsums[c * D + gj] / n;
        float cov = (s - n * mi * mj) / (n - 1.f);
        float contrib;
        if (q == 2) {
            contrib = 2.f * cov * cov * (1.f / (float)D);
        } else if (il == jl) {
            float sd = sqrtf(cov + EPSF);
            contrib = fmaxf(1.f - sd, 0.f) * (1.f / (float)D);
        } else {
            contrib = cov * cov * (1.f / (float)D);
        }
        local += contrib;
    }
    red[t] = local;
    __syncthreads();
    for (int s = 128; s > 0; s >>= 1) {
        if (t < s) red[t] += red[t + s];
        __syncthreads();
    }
    if (t == 0) atomicAdd(out, red[0]);
}

// ===========================================================================
// Fallback path (round 11, proven): fused gather quadrant Gram
// ===========================================================================
__device__ __forceinline__ uint4 pack8(const f32x4& a, const f32x4& b) {
    return make_uint4(
        (unsigned int)f2bf(a[0]) | ((unsigned int)f2bf(a[1]) << 16),
        (unsigned int)f2bf(a[2]) | ((unsigned int)f2bf(a[3]) << 16),
        (unsigned int)f2bf(b[0]) | ((unsigned int)f2bf(b[1]) << 16),
        (unsigned int)f2bf(b[2]) | ((unsigned int)f2bf(b[3]) << 16));
}
__device__ __forceinline__ void st_tile(unsigned char* lds, const uint4* R,
                                        int kblk, int cblkg) {
    #pragma unroll
    for (int cc = 0; cc < 8; ++cc) {
        int wd = cc >> 1;
        int sh = (cc & 1) * 16;
        unsigned int e0 = (((const unsigned int*)&R[0])[wd] >> sh) & 0xffffu;
        unsigned int e1 = (((const unsigned int*)&R[1])[wd] >> sh) & 0xffffu;
        unsigned int e2 = (((const unsigned int*)&R[2])[wd] >> sh) & 0xffffu;
        unsigned int e3 = (((const unsigned int*)&R[3])[wd] >> sh) & 0xffffu;
        int ccol = cblkg * 8 + cc;
        int byt = ccol * 128 + ((kblk * 8) ^ (cc << 4));
        *(uint2*)(lds + byt) = make_uint2(e0 | (e1 << 16), e2 | (e3 << 16));
    }
}

__global__ __launch_bounds__(256) void k_gram_f(
    const float* __restrict__ X, const int* __restrict__ idx,
    const int* __restrict__ counts, const int* __restrict__ offsets,
    unsigned short* __restrict__ part, float* __restrict__ csums)
{
    __shared__ __align__(16) unsigned char lds[64 * 256 * 2];
    int t = threadIdx.x;
    int lane = t & 63;
    int w = t >> 6;
    int wrow = w >> 1, wcol = w & 1;
    int kblk = t & 15;
    int cblk0 = t >> 4;

    int nch[NCLS], ofch[NCLS];
    int T = 0;
    for (int c = 0; c < NCLS; ++c) {
        nch[c] = (counts[c] + CHUNK - 1) / CHUNK;
        ofch[c] = T;
        T += nch[c];
    }
    const f32x4 zf = {0.f, 0.f, 0.f, 0.f};

    for (int wk = blockIdx.x; wk < 3 * T; wk += gridDim.x) {
        int item = wk / 3;
        int q = wk - item * 3;
        int c = 0;
        while (c < NCLS - 1 && item >= ofch[c + 1]) ++c;
        int chunk = item - ofch[c];
        int base = offsets[c] + chunk * CHUNK;
        int rows = min(CHUNK, counts[c] - chunk * CHUNK);
        int ntiles = (rows + 63) >> 6;

        int colbg = (q == 1) ? 128 : 0;
        bool two = (q == 2);
        int bbase = two ? 128 : 0;

        f32x4 acc[4][4];
        #pragma unroll
        for (int i = 0; i < 4; ++i)
            #pragma unroll
            for (int j = 0; j < 4; ++j)
                #pragma unroll
                for (int r = 0; r < 4; ++r) acc[i][j][r] = 0.f;
        float sumv[8];
        #pragma unroll
        for (int e = 0; e < 8; ++e) sumv[e] = 0.f;

        for (int kt = 0; kt < ntiles; ++kt) {
            int rid[4];
            #pragma unroll
            for (int j = 0; j < 4; ++j) {
                int r = kt * 64 + kblk * 4 + j;
                rid[j] = idx[base + min(r, rows - 1)];
            }
            uint4 R0[4];
            #pragma unroll
            for (int j = 0; j < 4; ++j) {
                int r = kt * 64 + kblk * 4 + j;
                const float* rp = X + ((size_t)rid[j] << 8) + colbg + cblk0 * 8;
                f32x4 a = *(const f32x4*)rp;
                f32x4 b = *(const f32x4*)(rp + 4);
                if (r >= rows) { a = zf; b = zf; }
                #pragma unroll
                for (int e = 0; e < 4; ++e) { sumv[e] += a[e]; sumv[4 + e] += b[e]; }
                R0[j] = pack8(a, b);
            }
            uint4 R1[4];
            if (two) {
                #pragma unroll
                for (int j = 0; j < 4; ++j) {
                    int r = kt * 64 + kblk * 4 + j;
                    const float* rp = X + ((size_t)rid[j] << 8) + 128 + cblk0 * 8;
                    f32x4 a = *(const f32x4*)rp;
                    f32x4 b = *(const f32x4*)(rp + 4);
                    if (r >= rows) { a = zf; b = zf; }
                    R1[j] = pack8(a, b);
                }
            }
            __syncthreads();
            st_tile(lds, R0, kblk, cblk0);
            if (two) st_tile(lds, R1, kblk, cblk0 + 16);
            __syncthreads();
            #pragma unroll
            for (int ks = 0; ks < 2; ++ks) {
                int kb2 = ks * 64 + ((lane >> 4) << 4);
                int swz = (lane & 7) << 4;
                bf16x8 bfr[4];
                #pragma unroll
                for (int tj = 0; tj < 4; ++tj) {
                    int ccol = bbase + wcol * 64 + tj * 16 + (lane & 15);
                    bfr[tj] = __builtin_bit_cast(bf16x8,
                        *(const uint4*)(lds + ccol * 128 + (kb2 ^ swz)));
                }
                #pragma unroll
                for (int ti = 0; ti < 4; ++ti) {
                    int ccol = wrow * 64 + ti * 16 + (lane & 15);
                    bf16x8 af = __builtin_bit_cast(bf16x8,
                        *(const uint4*)(lds + ccol * 128 + (kb2 ^ swz)));
                    #pragma unroll
                    for (int tj = 0; tj < 4; ++tj)
                        acc[ti][tj] = __builtin_amdgcn_mfma_f32_16x16x32_bf16(
                            af, bfr[tj], acc[ti][tj], 0, 0, 0);
                }
            }
        }

        unsigned short* dst = part + (size_t)wk * QLEN;
        #pragma unroll
        for (int ti = 0; ti < 4; ++ti) {
            int row0 = wrow * 64 + ti * 16 + ((lane >> 4) << 2);
            #pragma unroll
            for (int tj = 0; tj < 4; ++tj) {
                int col = wcol * 64 + tj * 16 + (lane & 15);
                #pragma unroll
                for (int r = 0; r < 4; ++r)
                    dst[(row0 + r) * 128 + col] = f2bf(acc[ti][tj][r]);
            }
        }
        #pragma unroll
        for (int s = 1; s < 16; s <<= 1)
            #pragma unroll
            for (int e = 0; e < 8; ++e)
                sumv[e] += __shfl_xor(sumv[e], s, 64);
        if (q < 2 && (t & 15) == 0) {
            float* cs = csums + (size_t)item * D + colbg + cblk0 * 8;
            #pragma unroll
            for (int e = 0; e < 8; ++e) cs[e] = sumv[e];
        }
        __syncthreads();
    }
}

__global__ __launch_bounds__(256) void k_loss_f(
    const unsigned short* __restrict__ part, const float* __restrict__ gsums,
    const int* __restrict__ counts, float* __restrict__ out)
{
    __shared__ float red[256];
    int t = threadIdx.x;
    int nch[NCLS], ofch[NCLS];
    int T = 0;
    for (int c = 0; c < NCLS; ++c) {
        nch[c] = (counts[c] + CHUNK - 1) / CHUNK;
        ofch[c] = T;
        T += nch[c];
    }
    float local = 0.f;
    const int total = NCLS * 3 * QLEN;
    for (int idx = blockIdx.x * blockDim.x + t; idx < total; idx += gridDim.x * blockDim.x) {
        int c = idx / (3 * QLEN);
        int rem = idx - c * (3 * QLEN);
        int q = rem >> 14;
        int ij = rem & (QLEN - 1);
        int il = ij >> 7, jl = ij & 127;
        int gi = il + ((q == 1) ? 128 : 0);
        int gj = jl + ((q == 0) ? 0 : 128);
        const unsigned short* p = part + ((size_t)(ofch[c] * 3 + q)) * QLEN + ij;
        float s = 0.f;
        for (int k = 0; k < nch[c]; ++k) s += bf2f(p[(size_t)k * 3 * QLEN]);
        float n  = (float)counts[c];
        float mi = gsums[c * D + gi] / n;
        float mj = gsums[c * D + gj] / n;
        float cov = (s - n * mi * mj) / (n - 1.f);
        float contrib;
        if (q == 2) {
            contrib = 2.f * cov * cov * (1.f / (float)D);
        } else if (il == jl) {
            float sd = sqrtf(cov + EPSF);
            contrib = fmaxf(1.f - sd, 0.f) * (1.f / (float)D);
        } else {
            contrib = cov * cov * (1.f / (float)D);
        }
        local += contrib;
    }
    red[t] = local;
    __syncthreads();
    for (int s = 128; s > 0; s >>= 1) {
        if (t < s) red[t] += red[t + s];
        __syncthreads();
    }
    if (t == 0) atomicAdd(out, red[0]);
}

// ---------------------------------------------------------------------------
extern "C" void kernel_launch(void* const* d_in, const int* in_sizes, int n_in,
                              void* d_out, int out_size, void* d_ws, size_t ws_size,
                              hipStream_t stream)
{
    const float* X      = (const float*)d_in[0];
    const int*   labels = (const int*)d_in[1];
    int nfeat = in_sizes[0];
    int nlab  = in_sizes[1];
    int nrows = nfeat / D;            // 131072
    int vfac  = nrows / nlab;         // 2 views per sample

    char* ws = (char*)d_ws;

    // ---- new-path layout ----
    size_t sz_sT    = (size_t)TCMAX * CHUNK * D * 2;      // 68.9 MB
    size_t off_cs   = sz_sT;
    size_t sz_cs    = (size_t)TCMAX * D * 4;              // 269 KB
    size_t off_cnt  = (off_cs + sz_cs + 255) & ~(size_t)255;
    size_t off_ofs  = off_cnt + 64;
    size_t off_cur  = off_ofs + 64;
    size_t off_slab = (off_cur + 64 + 255) & ~(size_t)255;
    size_t unit     = (size_t)NCLS * 3 * QLEN * 2;        // 786 KB per G

    int G = 0;
    if (ws_size > off_slab + 4096) G = (int)((ws_size - off_slab - 4096) / unit);
    if (G > 32) G = 32;

    if (G >= 12) {
        // -------- streaming path --------
        unsigned short* sortedT = (unsigned short*)(ws);
        float*          csums   = (float*)(ws + off_cs);
        int*            counts  = (int*)(ws + off_cnt);
        int*            offsets = (int*)(ws + off_ofs);
        int*            cursor  = (int*)(ws + off_cur);
        unsigned short* part    = (unsigned short*)(ws + off_slab);
        int*            idx     = (int*)(ws + off_slab);  // dead before part written
        float*          gsums   = (float*)(ws + off_cnt + 256);  // 8KB after counters
        // place gsums safely: counters use 192 B; put gsums at off_cur+64
        gsums = (float*)(ws + off_cur + 64);
        // gsums needs 8 KB -> ensure slab starts after it
        // (off_slab = align(off_cur + 64 + 255)) -- overlap! fix: gsums in csums tail
        gsums = csums + (size_t)TCMAX * D;                // unused csums tail? No.
        // csums sized exactly TCMAX*D; append gsums after slabs instead:
        gsums = (float*)(ws + off_slab + (size_t)G * unit);

        hipMemsetAsync(counts, 0, 64, stream);
        hipMemsetAsync(d_out, 0, (size_t)out_size * sizeof(float), stream);

        k_hist<<<64, 256, 0, stream>>>(labels, nlab, vfac, counts);
        k_offsets<<<1, 64, 0, stream>>>(counts, offsets, cursor);
        k_idx<<<(nrows + SEG - 1) / SEG, SEG, 0, stream>>>(labels, nrows, vfac, cursor, idx);
        k_tr<<<2 * TCMAX, 512, 0, stream>>>(X, idx, counts, offsets, sortedT, csums);
        k_gram_s<<<NCLS * 3 * G, 256, 0, stream>>>(sortedT, counts, part, G);
        k_gsum<<<NCLS, 256, 0, stream>>>(csums, counts, gsums);
        k_loss_s<<<512, 256, 0, stream>>>(part, gsums, counts, (float*)d_out, G);
    } else {
        // -------- fallback: round-11 layout --------
        size_t off_idx  = 0;
        size_t sz_idx   = (size_t)nrows * 4;
        size_t off_part = (off_idx + sz_idx + 255) & ~(size_t)255;
        size_t sz_part  = (size_t)3 * TMAXF * QLEN * 2;
        size_t off_cs2  = (off_part + sz_part + 255) & ~(size_t)255;
        size_t sz_cs2   = (size_t)TMAXF * D * 4;
        size_t off_gs   = (off_cs2 + sz_cs2 + 255) & ~(size_t)255;
        size_t sz_gs    = (size_t)NCLS * D * 4;
        size_t off_cn2  = (off_gs + sz_gs + 255) & ~(size_t)255;
        size_t off_of2  = off_cn2 + 64;
        size_t off_cu2  = off_of2 + 64;

        int*            idx     = (int*)(ws + off_idx);
        unsigned short* part    = (unsigned short*)(ws + off_part);
        float*          csums   = (float*)(ws + off_cs2);
        float*          gsums   = (float*)(ws + off_gs);
        int*            counts  = (int*)(ws + off_cn2);
        int*            offsets = (int*)(ws + off_of2);
        int*            cursor  = (int*)(ws + off_cu2);

        hipMemsetAsync(counts, 0, 64, stream);
        hipMemsetAsync(d_out, 0, (size_t)out_size * sizeof(float), stream);

        k_hist<<<64, 256, 0, stream>>>(labels, nlab, vfac, counts);
        k_offsets<<<1, 64, 0, stream>>>(counts, offsets, cursor);
        k_idx<<<(nrows + SEG - 1) / SEG, SEG, 0, stream>>>(labels, nrows, vfac, cursor, idx);
        k_gram_f<<<3 * TMAXF, 256, 0, stream>>>(X, idx, counts, offsets, part, csums);
        k_gsum<<<NCLS, 256, 0, stream>>>(csums, counts, gsums);
        k_loss_f<<<512, 256, 0, stream>>>(part, gsums, counts, (float*)d_out);
    }
}